// Round 4
// baseline (17530.988 us; speedup 1.0000x reference)
//
#include <hip/hip_runtime.h>
#include <hip/hip_bf16.h>

#define HID 1024
#define NBATCH 16
#define LSEQ 2048
#define OBSD 128
#define ACTD 16
#define INSZ 144

typedef __bf16 bf16x8 __attribute__((ext_vector_type(8)));
typedef float f32x4 __attribute__((ext_vector_type(4)));
typedef unsigned long long ull;
typedef ull ull2 __attribute__((ext_vector_type(2)));

// ---- XCD-scope (sc0-only: bypass L1, meet at the XCD-local L2) primitives ----
__device__ __forceinline__ void st8_sc0(ull* p, ull v) {
    asm volatile("global_store_dwordx2 %0, %1, off sc0" :: "v"(p), "v"(v) : "memory");
}
__device__ __forceinline__ void st4_sc0(int* p, int v) {
    asm volatile("global_store_dword %0, %1, off sc0" :: "v"(p), "v"(v) : "memory");
}
__device__ __forceinline__ int ld4_sc0(const int* p) {
    int r;
    asm volatile("global_load_dword %0, %1, off sc0\n\ts_waitcnt vmcnt(0)"
                 : "=v"(r) : "v"(p) : "memory");
    return r;
}

// Monolithic sweep: 32x16B coalesced sc0 loads + waitcnt in ONE asm (defs and
// wait in the same statement -> no compiler-copy/RA hazard on pending regs).
#define SWEEP_SC0(Q, PP)                                                       \
    {                                                                          \
        char* _p0 = (PP);                                                      \
        char* _p1 = (PP) + 8192;                                               \
        char* _p2 = (PP) + 16384;                                              \
        char* _p3 = (PP) + 24576;                                              \
        asm volatile(                                                          \
            "global_load_dwordx4 %[q0], %[p0], off offset:-4096 sc0\n\t"       \
            "global_load_dwordx4 %[q1], %[p0], off offset:-3072 sc0\n\t"       \
            "global_load_dwordx4 %[q2], %[p0], off offset:-2048 sc0\n\t"       \
            "global_load_dwordx4 %[q3], %[p0], off offset:-1024 sc0\n\t"       \
            "global_load_dwordx4 %[q4], %[p0], off offset:0 sc0\n\t"           \
            "global_load_dwordx4 %[q5], %[p0], off offset:1024 sc0\n\t"        \
            "global_load_dwordx4 %[q6], %[p0], off offset:2048 sc0\n\t"        \
            "global_load_dwordx4 %[q7], %[p0], off offset:3072 sc0\n\t"        \
            "global_load_dwordx4 %[q8], %[p1], off offset:-4096 sc0\n\t"       \
            "global_load_dwordx4 %[q9], %[p1], off offset:-3072 sc0\n\t"       \
            "global_load_dwordx4 %[q10], %[p1], off offset:-2048 sc0\n\t"      \
            "global_load_dwordx4 %[q11], %[p1], off offset:-1024 sc0\n\t"      \
            "global_load_dwordx4 %[q12], %[p1], off offset:0 sc0\n\t"          \
            "global_load_dwordx4 %[q13], %[p1], off offset:1024 sc0\n\t"       \
            "global_load_dwordx4 %[q14], %[p1], off offset:2048 sc0\n\t"       \
            "global_load_dwordx4 %[q15], %[p1], off offset:3072 sc0\n\t"       \
            "global_load_dwordx4 %[q16], %[p2], off offset:-4096 sc0\n\t"      \
            "global_load_dwordx4 %[q17], %[p2], off offset:-3072 sc0\n\t"      \
            "global_load_dwordx4 %[q18], %[p2], off offset:-2048 sc0\n\t"      \
            "global_load_dwordx4 %[q19], %[p2], off offset:-1024 sc0\n\t"      \
            "global_load_dwordx4 %[q20], %[p2], off offset:0 sc0\n\t"          \
            "global_load_dwordx4 %[q21], %[p2], off offset:1024 sc0\n\t"       \
            "global_load_dwordx4 %[q22], %[p2], off offset:2048 sc0\n\t"       \
            "global_load_dwordx4 %[q23], %[p2], off offset:3072 sc0\n\t"       \
            "global_load_dwordx4 %[q24], %[p3], off offset:-4096 sc0\n\t"      \
            "global_load_dwordx4 %[q25], %[p3], off offset:-3072 sc0\n\t"      \
            "global_load_dwordx4 %[q26], %[p3], off offset:-2048 sc0\n\t"      \
            "global_load_dwordx4 %[q27], %[p3], off offset:-1024 sc0\n\t"      \
            "global_load_dwordx4 %[q28], %[p3], off offset:0 sc0\n\t"          \
            "global_load_dwordx4 %[q29], %[p3], off offset:1024 sc0\n\t"       \
            "global_load_dwordx4 %[q30], %[p3], off offset:2048 sc0\n\t"       \
            "global_load_dwordx4 %[q31], %[p3], off offset:3072 sc0\n\t"       \
            "s_waitcnt vmcnt(0)"                                               \
            : [q0] "=&v"(Q[0]), [q1] "=&v"(Q[1]), [q2] "=&v"(Q[2]),            \
              [q3] "=&v"(Q[3]), [q4] "=&v"(Q[4]), [q5] "=&v"(Q[5]),            \
              [q6] "=&v"(Q[6]), [q7] "=&v"(Q[7]), [q8] "=&v"(Q[8]),            \
              [q9] "=&v"(Q[9]), [q10] "=&v"(Q[10]), [q11] "=&v"(Q[11]),        \
              [q12] "=&v"(Q[12]), [q13] "=&v"(Q[13]), [q14] "=&v"(Q[14]),      \
              [q15] "=&v"(Q[15]), [q16] "=&v"(Q[16]), [q17] "=&v"(Q[17]),      \
              [q18] "=&v"(Q[18]), [q19] "=&v"(Q[19]), [q20] "=&v"(Q[20]),      \
              [q21] "=&v"(Q[21]), [q22] "=&v"(Q[22]), [q23] "=&v"(Q[23]),      \
              [q24] "=&v"(Q[24]), [q25] "=&v"(Q[25]), [q26] "=&v"(Q[26]),      \
              [q27] "=&v"(Q[27]), [q28] "=&v"(Q[28]), [q29] "=&v"(Q[29]),      \
              [q30] "=&v"(Q[30]), [q31] "=&v"(Q[31])                           \
            : [p0] "v"(_p0), [p1] "v"(_p1), [p2] "v"(_p2), [p3] "v"(_p3)       \
            : "memory");                                                       \
    }

// ---------------- obs_target copy ----------------
__global__ __launch_bounds__(256) void k_copy_target(const float* __restrict__ obs,
                                                     float* __restrict__ tgt) {
    long long i = (long long)blockIdx.x * blockDim.x + threadIdx.x; // float4 idx
    const long long per_n = (long long)LSEQ * OBSD / 4;
    if (i >= (long long)NBATCH * per_n) return;
    int n = (int)(i / per_n);
    long long r = i - (long long)n * per_n;
    const float4* src = (const float4*)obs;
    float4* dst = (float4*)tgt;
    dst[i] = src[(long long)n * (((LSEQ + 1) * OBSD) / 4) + (OBSD / 4) + r];
}

// ---------------- xproj: xp[l][n][d] -> written into ht[n][l][d] ----------------
__global__ __launch_bounds__(256) void k_xproj(const float* __restrict__ obs,
                                               const float* __restrict__ act,
                                               const float* __restrict__ W_ih,
                                               const float* __restrict__ bias,
                                               const float* __restrict__ noise,
                                               float* __restrict__ ht) {
    __shared__ float xs[NBATCH][INSZ];
    const int l = blockIdx.x;
    const int t = threadIdx.x;

    for (int i = t; i < NBATCH * INSZ; i += 256) {
        int n = i / INSZ, c = i % INSZ;
        float v = (c < OBSD) ? obs[((long long)n * (LSEQ + 1) + l) * OBSD + c]
                             : act[((long long)n * LSEQ + l) * ACTD + (c - OBSD)];
        xs[n][c] = v;
    }
    __syncthreads();

    const int d0 = t * 4;
    float4 bi = *(const float4*)(bias + d0);
    float4 no = *(const float4*)(noise + (long long)l * HID + d0);
    float acc[NBATCH][4];
#pragma unroll
    for (int nn = 0; nn < NBATCH; ++nn) {
        acc[nn][0] = bi.x + no.x; acc[nn][1] = bi.y + no.y;
        acc[nn][2] = bi.z + no.z; acc[nn][3] = bi.w + no.w;
    }
    for (int k = 0; k < INSZ; k += 4) {
        float4 w[4];
#pragma unroll
        for (int i = 0; i < 4; ++i)
            w[i] = *(const float4*)(W_ih + (long long)(d0 + i) * INSZ + k);
#pragma unroll
        for (int nn = 0; nn < NBATCH; ++nn) {
            float4 xv = *(const float4*)&xs[nn][k];
#pragma unroll
            for (int i = 0; i < 4; ++i)
                acc[nn][i] += xv.x * w[i].x + xv.y * w[i].y + xv.z * w[i].z + xv.w * w[i].w;
        }
    }
#pragma unroll
    for (int nn = 0; nn < NBATCH; ++nn) {
        float4 v = make_float4(acc[nn][0], acc[nn][1], acc[nn][2], acc[nn][3]);
        *(float4*)(ht + ((long long)nn * LSEQ + l) * HID + d0) = v;
    }
}

// ---------------- persistent scan, single-XCD L2 exchange ----------------
// 1024 claimer blocks x 64 threads. Blocks read HW_REG_XCC_ID (hwreg 20) and
// claim a slot on their XCD; first XCD to fill 64 slots wins (pigeonhole over
// >=1024 co-resident blocks). Winning waves own rows [16s,16s+16) and exchange
// h through the shared per-XCD L2 via sc0 ops. Tag/validation as R3. On
// timeout (wrong XCC read / pathological scheduling) a wave permanently
// degrades to agent-scope (IC) exchange: slow but correct.
__global__ __launch_bounds__(64, 1) void k_scan(const float* __restrict__ W_hh,
                                                float* __restrict__ ht,
                                                unsigned char* __restrict__ ws) {
    const int lane = threadIdx.x;

    // ---- claim phase ----
    int xcd = __builtin_amdgcn_s_getreg((3 << 11) | 20) & 15; // HW_REG_XCC_ID[3:0]
    int* cnt = (int*)(ws + 65792);
    int* winner = (int*)(ws + 65856);
    int c0 = 0;
    if (lane == 0) c0 = atomicAdd(&cnt[xcd], 1);
    const int s = __shfl(c0, 0);
    if (lane == 0 && s == 63) atomicCAS(winner, 0, xcd + 1);
    if (s >= 64) return;
    int win;
    do {
        win = __hip_atomic_load(winner, __ATOMIC_RELAXED, __HIP_MEMORY_SCOPE_AGENT);
    } while (win == 0);
    if (win - 1 != xcd) return;

    // ---- setup ----
    const int n = lane & 15;
    const int quad = lane >> 4;
    const int jA = 16 * s + n;
    const int jq = 16 * s + 4 * quad;
    int* flags = (int*)(ws + 65536);

    bf16x8 wf[32];
#pragma unroll
    for (int t = 0; t < 32; ++t) {
        const float* p = W_hh + (long long)jA * HID + t * 32 + quad * 8;
        bf16x8 v;
#pragma unroll
        for (int e = 0; e < 8; ++e) v[e] = (__bf16)p[e];
        wf[t] = v;
    }
    float wdg[4], wdgb[4];
#pragma unroll
    for (int r = 0; r < 4; ++r) {
        float w = W_hh[(long long)(jq + r) * HID + (jq + r)];
        wdg[r] = w;
        wdgb[r] = (float)(__bf16)w;
    }

    const int coff = 512 * (quad >> 1) + 32 * n + 16 * (quad & 1); // consumer byte off
    const int myq = s * 64 + n * 4 + quad;                         // producer ull slot
    char* pA = (char*)ws + coff + 4096;          // buf0 sweep base
    char* pB = (char*)ws + 32768 + coff + 4096;  // buf1 sweep base

    bool degraded = false;
    f32x4 hprev;
    float hbprev[4];
    ull lastq;

    // ---- step 0 ----
    {
        f32x4 xp = *(const f32x4*)(ht + ((long long)n * LSEQ) * HID + jq);
        f32x4 h;
#pragma unroll
        for (int r = 0; r < 4; ++r) h[r] = fmaxf(xp[r], 0.f);
        ull qo = 0;
#pragma unroll
        for (int r = 0; r < 4; ++r) {
            __bf16 x = (__bf16)h[r];
            hbprev[r] = (float)x;
            qo |= (ull)__builtin_bit_cast(unsigned short, x) << (16 * r);
        }
        st8_sc0((ull*)ws + myq, qo); // tag 0
        if (lane == 0) st4_sc0(&flags[s], 1);
        *(f32x4*)(ht + ((long long)n * LSEQ) * HID + jq) = h;
        hprev = h;
        lastq = qo;
    }

    // ---- steps 1..L-1 ----
    for (int l = 1; l < LSEQ; ++l) {
        f32x4 xp = *(const f32x4*)(ht + ((long long)n * LSEQ + l) * HID + jq);

        const int sb = (l - 1) & 1;
        const ull te = (ull)((((l - 1) >> 1) & 1) << 15); // expected tag bit

        ull2 q[32];
        bool done = false;

        if (!degraded) {
            int tries = 0;
            bool fok;
            do {
                int fv = ld4_sc0(&flags[lane]);
                fok = __all(fv >= l);
            } while (!fok && ++tries < 4096);
            if (fok) {
                char* pp = sb ? pB : pA;
                for (int att = 0; att < 16 && !done; ++att) {
                    SWEEP_SC0(q, pp);
                    unsigned int bad = 0;
#pragma unroll
                    for (int t = 0; t < 32; ++t) {
                        q[t].x ^= te; q[t].y ^= te;
                        bad |= (unsigned int)q[t].x | (unsigned int)q[t].y;
                    }
                    done = __all((bad & 0x8000u) == 0u);
                }
            }
            if (!done) degraded = true;
        }
        if (!done) { // agent-scope fallback (correct under any grouping)
            ull* prevpub = (ull*)(ws + sb * 32768) + myq;
            const ull* hbn = (const ull*)(ws + sb * 32768);
            const int bi = coff >> 3;
            do {
                __hip_atomic_store(prevpub, lastq, __ATOMIC_RELAXED, __HIP_MEMORY_SCOPE_AGENT);
#pragma unroll
                for (int t = 0; t < 32; ++t) {
                    q[t].x = __hip_atomic_load(hbn + t * 128 + bi,
                                               __ATOMIC_RELAXED, __HIP_MEMORY_SCOPE_AGENT);
                    q[t].y = __hip_atomic_load(hbn + t * 128 + bi + 1,
                                               __ATOMIC_RELAXED, __HIP_MEMORY_SCOPE_AGENT);
                }
                unsigned int bad = 0;
#pragma unroll
                for (int t = 0; t < 32; ++t) {
                    q[t].x ^= te; q[t].y ^= te;
                    bad |= (unsigned int)q[t].x | (unsigned int)q[t].y;
                }
                done = __all((bad & 0x8000u) == 0u);
            } while (!done);
        }

        f32x4 a0 = xp;
        f32x4 a1 = {0.f, 0.f, 0.f, 0.f};
        f32x4 a2 = {0.f, 0.f, 0.f, 0.f};
        f32x4 a3 = {0.f, 0.f, 0.f, 0.f};
#pragma unroll
        for (int t = 0; t < 32; t += 4) {
            union { ull2 u; bf16x8 v; } c0v, c1v, c2v, c3v;
            c0v.u = q[t]; c1v.u = q[t + 1]; c2v.u = q[t + 2]; c3v.u = q[t + 3];
            a0 = __builtin_amdgcn_mfma_f32_16x16x32_bf16(wf[t], c0v.v, a0, 0, 0, 0);
            a1 = __builtin_amdgcn_mfma_f32_16x16x32_bf16(wf[t + 1], c1v.v, a1, 0, 0, 0);
            a2 = __builtin_amdgcn_mfma_f32_16x16x32_bf16(wf[t + 2], c2v.v, a2, 0, 0, 0);
            a3 = __builtin_amdgcn_mfma_f32_16x16x32_bf16(wf[t + 3], c3v.v, a3, 0, 0, 0);
        }

#pragma unroll
        for (int r = 0; r < 4; ++r) {
            float v = (a0[r] + a1[r]) + (a2[r] + a3[r]);
            v += wdg[r] * hprev[r] - wdgb[r] * hbprev[r]; // exact fp32 diagonal
            hprev[r] = fmaxf(v, 0.f);
        }

        // publish step l: buf l&1, tag (l>>1)&1 in sign of halfword 0
        const ull tw = (ull)((l >> 1) & 1) << 15;
        ull qo = 0;
#pragma unroll
        for (int r = 0; r < 4; ++r) {
            __bf16 x = (__bf16)hprev[r];
            hbprev[r] = (float)x;
            qo |= (ull)__builtin_bit_cast(unsigned short, x) << (16 * r);
        }
        qo |= tw;
        st8_sc0((ull*)(ws + (l & 1) * 32768) + myq, qo);
        lastq = qo;
        if (lane == 0) st4_sc0(&flags[s], l + 1);
        *(f32x4*)(ht + ((long long)n * LSEQ + l) * HID + jq) = hprev;
    }
}

// ---------------- y = sigmoid(h @ W_out^T) ----------------
__global__ __launch_bounds__(256) void k_yout(const float* __restrict__ ht,
                                              const float* __restrict__ W_out,
                                              float* __restrict__ y) {
    __shared__ float hs[64 * 66];
    __shared__ float wt[128 * 66];
    const int t = threadIdx.x;
    const long long R0 = (long long)blockIdx.x * 64;
    const int rg = t >> 4;
    const int og = t & 15;

    float acc[4][8];
#pragma unroll
    for (int r = 0; r < 4; ++r)
#pragma unroll
        for (int o = 0; o < 8; ++o) acc[r][o] = 0.f;

    for (int kc = 0; kc < HID; kc += 64) {
        __syncthreads();
#pragma unroll
        for (int i = 0; i < 4; ++i) {
            int idx = t + i * 256;
            int r = idx >> 4, c = (idx & 15) * 4;
            float4 v = *(const float4*)(ht + (R0 + r) * HID + kc + c);
            *(float2*)&hs[r * 66 + c] = make_float2(v.x, v.y);
            *(float2*)&hs[r * 66 + c + 2] = make_float2(v.z, v.w);
        }
#pragma unroll
        for (int i = 0; i < 8; ++i) {
            int idx = t + i * 256;
            int o = idx >> 4, c = (idx & 15) * 4;
            float4 v = *(const float4*)(W_out + (long long)o * HID + kc + c);
            *(float2*)&wt[o * 66 + c] = make_float2(v.x, v.y);
            *(float2*)&wt[o * 66 + c + 2] = make_float2(v.z, v.w);
        }
        __syncthreads();
#pragma unroll
        for (int kk = 0; kk < 64; kk += 2) {
            float2 hv[4], wv[8];
#pragma unroll
            for (int r = 0; r < 4; ++r) hv[r] = *(const float2*)&hs[(rg * 4 + r) * 66 + kk];
#pragma unroll
            for (int o = 0; o < 8; ++o) wv[o] = *(const float2*)&wt[(og * 8 + o) * 66 + kk];
#pragma unroll
            for (int r = 0; r < 4; ++r)
#pragma unroll
                for (int o = 0; o < 8; ++o)
                    acc[r][o] += hv[r].x * wv[o].x + hv[r].y * wv[o].y;
        }
    }
#pragma unroll
    for (int r = 0; r < 4; ++r) {
        long long R = R0 + rg * 4 + r;
        float out[8];
#pragma unroll
        for (int o = 0; o < 8; ++o) out[o] = 1.f / (1.f + __expf(-acc[r][o]));
        *(float4*)(y + R * OBSD + og * 8) = make_float4(out[0], out[1], out[2], out[3]);
        *(float4*)(y + R * OBSD + og * 8 + 4) = make_float4(out[4], out[5], out[6], out[7]);
    }
}

extern "C" void kernel_launch(void* const* d_in, const int* in_sizes, int n_in,
                              void* d_out, int out_size, void* d_ws, size_t ws_size,
                              hipStream_t stream) {
    const float* obs = (const float*)d_in[0];
    const float* act = (const float*)d_in[1];
    const float* W_ih = (const float*)d_in[2];
    const float* W_hh = (const float*)d_in[3];
    const float* bias = (const float*)d_in[4];
    const float* W_out = (const float*)d_in[5];
    const float* noise = (const float*)d_in[6];

    float* y = (float*)d_out;                                   // 16*2048*128
    float* ht = y + (long long)NBATCH * LSEQ * OBSD;            // 16*2048*1024
    float* tgt = ht + (long long)NBATCH * LSEQ * HID;           // 16*2048*128
    unsigned char* ws = (unsigned char*)d_ws;

    // zero control region: flags[64] @64K, cnt[16] @65792, winner @65856
    hipMemsetAsync(ws + 65536, 0, 1024, stream);
    k_copy_target<<<dim3(4096), dim3(256), 0, stream>>>(obs, tgt);
    k_xproj<<<dim3(LSEQ), dim3(256), 0, stream>>>(obs, act, W_ih, bias, noise, ht);
    k_scan<<<dim3(1024), dim3(64), 0, stream>>>(W_hh, ht, ws);
    k_yout<<<dim3(512), dim3(256), 0, stream>>>(ht, W_out, y);
}